// Round 3
// baseline (670.367 us; speedup 1.0000x reference)
//
#include <hip/hip_runtime.h>

// Problem constants: N=5, B=16, H=W=384, J=17
#define NF 5
#define NB 16
#define NH 384
#define NW 384
#define NJ 17
#define HW (NH * NW)
#define NPIX (NB * HW)                   // 2,359,296
#define UNSUP_BLOCKS (NPIX / 256)        // 9216

// charbonnier(x) = (x^2 + (1e-9)^2)^0.25
__device__ __forceinline__ float charb(float x) {
    return sqrtf(sqrtf(fmaf(x, x, 1e-18f)));
}

// ws layout: float[0]=sup_sum, [1]=denom count, [2]=unsup acc, u32[3]=ticket,
// float4[1 ..] = packed frm1 (B,H,W) RGBx

__global__ __launch_bounds__(256)
void repack_kp_kernel(const float* __restrict__ frm1,
                      const float* __restrict__ kps,
                      const float* __restrict__ pf,
                      float* __restrict__ ws, int do_pack) {
    int g = blockIdx.x * 256 + threadIdx.x;
    if (do_pack && g < NPIX) {
        int b = g / HW;
        int off = g - b * HW;
        const float* src = frm1 + (size_t)b * 3 * HW + off;
        ((float4*)ws)[1 + g] = make_float4(src[0], src[HW], src[2 * HW], 0.f);
    }
    if (g == 0) {                 // init accumulators for the next dispatch
        ws[2] = 0.f;
        ((unsigned int*)ws)[3] = 0u;
    }
    if (blockIdx.x == 0) {
        // ---- keypoint supervised loss (sparse: <= 272 points) ----
        __shared__ int cnt;
        __shared__ int ebase[NB * NJ];
        __shared__ float edx[NB * NJ], edy[NB * NJ];
        if (threadIdx.x == 0) cnt = 0;
        __syncthreads();
        for (int t = threadIdx.x; t < NB * NJ; t += 256) {
            int b = t / NJ, j = t - b * NJ;
            const float* k0 = kps + ((b * 2 + 0) * NJ + j) * 2;
            const float* k1 = kps + ((b * 2 + 1) * NJ + j) * 2;
            float x0 = k0[0], y0 = k0[1], x1 = k1[0], y1 = k1[1];
            bool valid = x0 >= 0.f && y0 >= 0.f && x1 >= 0.f && y1 >= 0.f &&
                         x0 < (float)NW && y0 < (float)NH &&
                         x1 < (float)NW && y1 < (float)NH;
            float dx = x1 - x0, dy = y1 - y0;
            if (valid && (dx != 0.f || dy != 0.f)) {
                int s = atomicAdd(&cnt, 1);
                ebase[s] = (b * 2) * HW + (int)floorf(y0) * NW + (int)floorf(x0);
                edx[s] = dx; edy[s] = dy;
            }
        }
        __syncthreads();
        int n = cnt;
        const float wts[NF] = {0.4096f, 0.512f, 0.64f, 0.8f, 1.0f};
        float local = 0.f;
        for (int q = threadIdx.x; q < n * NF; q += 256) {
            int e = q / NF, i = q - e * NF;
            int off = ebase[e] + i * (NB * 2 * HW);
            float ex = pf[off] - edx[e];
            float ey = pf[off + HW] - edy[e];
            local += wts[i] * sqrtf(fmaf(ex, ex, ey * ey));
        }
        for (int o = 32; o > 0; o >>= 1) local += __shfl_down(local, o, 64);
        __shared__ float ssum[4];
        int lane = threadIdx.x & 63, wid = threadIdx.x >> 6;
        if (lane == 0) ssum[wid] = local;
        __syncthreads();
        if (threadIdx.x == 0) {
            ws[0] = ssum[0] + ssum[1] + ssum[2] + ssum[3];
            ws[1] = (float)n;
        }
    }
}

template <bool PACKED>
__global__ __launch_bounds__(256)
void unsup_kernel(const float* __restrict__ pf, const float* __restrict__ frm0,
                  const float* __restrict__ frm1, float* __restrict__ ws,
                  float* __restrict__ out) {
    const int g = blockIdx.x * 256 + threadIdx.x;
    const int w = g % NW;
    const int t = g / NW;
    const int h = t % NH;
    const int b = t / NH;
    const int off = h * NW + w;
    const float SC = (float)(NW - 1) / (float)NW;

    // frm0: 3 channels for this pixel (read ONCE for all 5 levels; coalesced)
    const float* f0b = frm0 + b * 3 * HW + off;
    const float c0 = f0b[0];
    const float c1 = f0b[HW];
    const float c2 = f0b[2 * HW];

    const float4* packed = (const float4*)ws + 1 + b * HW;
    const float* img = frm1 + b * 3 * HW;
    const bool hasDown = (h < NH - 1);
    const bool hasRight = (w < NW - 1);
    const float xbase = (float)w;
    const float ybase = (float)h;

    float local = 0.f;
    const float* fb = pf + (b * 2) * HW + off;
    float wt = 0.4096f;
#pragma unroll 1
    for (int i = 0; i < NF; ++i, fb += NB * 2 * HW, wt *= 1.25f) {
        // issue all loads for this level up front (independent)
        float fx = fb[0];
        float fy = fb[HW];
        float dnx = 0.f, dny = 0.f, rtx = 0.f, rty = 0.f;
        if (hasDown)  { dnx = fb[NW];  dny = fb[NW + HW]; }
        if (hasRight) { rtx = fb[1];   rty = fb[HW + 1];  }

        float smooth = charb(fx - dnx) + charb(fy - dny) +
                       charb(fx - rtx) + charb(fy - rty);

        float xp = (fx + xbase) * SC;
        float yp = (fy + ybase) * SC;
        float x0f = floorf(xp), y0f = floorf(yp);
        float wx1 = xp - x0f, wx0 = 1.f - wx1;
        float wy1 = yp - y0f, wy0 = 1.f - wy1;
        bool vx0 = (x0f >= 0.f) && (x0f <= (float)(NW - 1));
        bool vx1 = (x0f >= -1.f) && (x0f <= (float)(NW - 2));
        bool vy0 = (y0f >= 0.f) && (y0f <= (float)(NH - 1));
        bool vy1 = (y0f >= -1.f) && (y0f <= (float)(NH - 2));
        float m00 = (vx0 && vy0) ? wx0 * wy0 : 0.f;
        float m10 = (vx1 && vy0) ? wx1 * wy0 : 0.f;
        float m01 = (vx0 && vy1) ? wx0 * wy1 : 0.f;
        float m11 = (vx1 && vy1) ? wx1 * wy1 : 0.f;
        int x0i = min(max((int)x0f, 0), NW - 1);
        int y0i = min(max((int)y0f, 0), NH - 1);
        int x1i = min(x0i + 1, NW - 1);
        int y1i = min(y0i + 1, NH - 1);

        float s0, s1, s2;
        if (PACKED) {
            const float4* row0 = packed + y0i * NW;
            const float4* row1 = packed + y1i * NW;
            float4 t00 = row0[x0i], t10 = row0[x1i];
            float4 t01 = row1[x0i], t11 = row1[x1i];
            s0 = m00 * t00.x + m10 * t10.x + m01 * t01.x + m11 * t11.x;
            s1 = m00 * t00.y + m10 * t10.y + m01 * t01.y + m11 * t11.y;
            s2 = m00 * t00.z + m10 * t10.z + m01 * t01.z + m11 * t11.z;
        } else {
            int i00 = y0i * NW + x0i, i10 = y0i * NW + x1i;
            int i01 = y1i * NW + x0i, i11 = y1i * NW + x1i;
            s0 = m00 * img[i00] + m10 * img[i10] + m01 * img[i01] + m11 * img[i11];
            s1 = m00 * img[HW + i00] + m10 * img[HW + i10] +
                 m01 * img[HW + i01] + m11 * img[HW + i11];
            s2 = m00 * img[2 * HW + i00] + m10 * img[2 * HW + i10] +
                 m01 * img[2 * HW + i01] + m11 * img[2 * HW + i11];
        }
        float phot = charb(s0 - c0) + charb(s1 - c1) + charb(s2 - c2);
        local += wt * (phot * (1.f / 3.f) + smooth * 0.5f);
    }

    // block reduce (256 threads = 4 waves)
    for (int o = 32; o > 0; o >>= 1) local += __shfl_down(local, o, 64);
    __shared__ float ssum[4];
    int lane = threadIdx.x & 63, wid = threadIdx.x >> 6;
    if (lane == 0) ssum[wid] = local;
    __syncthreads();
    if (threadIdx.x == 0) {
        atomicAdd(ws + 2, ssum[0] + ssum[1] + ssum[2] + ssum[3]);
        __threadfence();
        unsigned int old = atomicAdd((unsigned int*)ws + 3, 1u);
        if (old == (unsigned int)(gridDim.x - 1)) {
            // last block: finalize
            float uns = atomicAdd(ws + 2, 0.f);   // device-coherent read
            float denom = fmaxf(ws[1], 1.f);
            out[0] = uns * (1.f / (float)NB) + ws[0] / denom;
        }
    }
}

extern "C" void kernel_launch(void* const* d_in, const int* in_sizes, int n_in,
                              void* d_out, int out_size, void* d_ws, size_t ws_size,
                              hipStream_t stream) {
    const float* pf   = (const float*)d_in[0];  // (5,16,2,384,384)
    const float* kps  = (const float*)d_in[1];  // (16,2,17,2)
    const float* frm0 = (const float*)d_in[2];  // (16,3,384,384)
    const float* frm1 = (const float*)d_in[3];  // (16,3,384,384)
    float* out = (float*)d_out;
    float* ws  = (float*)d_ws;

    size_t need = 16 + (size_t)NPIX * 16;
    if (ws_size >= need) {
        repack_kp_kernel<<<(NPIX + 255) / 256, 256, 0, stream>>>(frm1, kps, pf, ws, 1);
        unsup_kernel<true><<<UNSUP_BLOCKS, 256, 0, stream>>>(pf, frm0, frm1, ws, out);
    } else {
        repack_kp_kernel<<<1, 256, 0, stream>>>(frm1, kps, pf, ws, 0);
        unsup_kernel<false><<<UNSUP_BLOCKS, 256, 0, stream>>>(pf, frm0, frm1, ws, out);
    }
}

// Round 4
// 302.605 us; speedup vs baseline: 2.2153x; 2.2153x over previous
//
#include <hip/hip_runtime.h>

// Problem constants: N=5, B=16, H=W=384, J=17
#define NF 5
#define NB 16
#define NH 384
#define NW 384
#define NJ 17
#define HW (NH * NW)
#define NPIX (NB * HW)                  // 2,359,296
#define UNSUP_BLOCKS (NF * NB * NH)     // 30720 blocks of 384 threads (1 row each)

// charbonnier(x) = (x^2 + (1e-9)^2)^0.25
__device__ __forceinline__ float charb(float x) {
    return sqrtf(sqrtf(fmaf(x, x, 1e-18f)));
}

// ws layout:
//   float ws[0]=sup_sum, ws[1]=denom, ws[2..3] pad
//   float4 packed[NPIX]      at (float4*)ws + 1        (packed RGBx frm1)
//   float  partials[UNSUP_BLOCKS] after the packed region (or at ws+4 if unpacked)

__global__ __launch_bounds__(256)
void repack_kp_kernel(const float* __restrict__ frm1,
                      const float* __restrict__ kps,
                      const float* __restrict__ pf,
                      float* __restrict__ ws, int do_pack) {
    int g = blockIdx.x * 256 + threadIdx.x;
    if (do_pack && g < NPIX) {
        int b = g / HW;
        int off = g - b * HW;
        const float* src = frm1 + (size_t)b * 3 * HW + off;
        ((float4*)ws)[1 + g] = make_float4(src[0], src[HW], src[2 * HW], 0.f);
    }
    if (blockIdx.x == 0) {
        // ---- keypoint supervised loss (sparse: <= 272 points) ----
        __shared__ int cnt;
        __shared__ int ebase[NB * NJ];
        __shared__ float edx[NB * NJ], edy[NB * NJ];
        if (threadIdx.x == 0) cnt = 0;
        __syncthreads();
        for (int t = threadIdx.x; t < NB * NJ; t += 256) {
            int b = t / NJ, j = t - b * NJ;
            const float* k0 = kps + ((b * 2 + 0) * NJ + j) * 2;
            const float* k1 = kps + ((b * 2 + 1) * NJ + j) * 2;
            float x0 = k0[0], y0 = k0[1], x1 = k1[0], y1 = k1[1];
            bool valid = x0 >= 0.f && y0 >= 0.f && x1 >= 0.f && y1 >= 0.f &&
                         x0 < (float)NW && y0 < (float)NH &&
                         x1 < (float)NW && y1 < (float)NH;
            float dx = x1 - x0, dy = y1 - y0;
            if (valid && (dx != 0.f || dy != 0.f)) {
                int s = atomicAdd(&cnt, 1);
                ebase[s] = (b * 2) * HW + (int)floorf(y0) * NW + (int)floorf(x0);
                edx[s] = dx; edy[s] = dy;
            }
        }
        __syncthreads();
        int n = cnt;
        float local = 0.f;
        for (int q = threadIdx.x; q < n * NF; q += 256) {
            int e = q / NF, i = q - e * NF;
            float wt = exp2f((float)(4 - i) * -0.32192809488736f);  // 0.8^(4-i)
            int off = ebase[e] + i * (NB * 2 * HW);
            float ex = pf[off] - edx[e];
            float ey = pf[off + HW] - edy[e];
            local += wt * sqrtf(fmaf(ex, ex, ey * ey));
        }
        for (int o = 32; o > 0; o >>= 1) local += __shfl_down(local, o, 64);
        __shared__ float ssum[4];
        int lane = threadIdx.x & 63, wid = threadIdx.x >> 6;
        if (lane == 0) ssum[wid] = local;
        __syncthreads();
        if (threadIdx.x == 0) {
            ws[0] = ssum[0] + ssum[1] + ssum[2] + ssum[3];
            ws[1] = (float)n;
        }
    }
}

// One block = one (level i, batch b, row h); thread = one pixel of that row.
// Straight-line body (no level loop) -> short independent dependency chains,
// max memory-level parallelism (round-1 structure, which achieved 3.55 TB/s).
template <bool PACKED>
__global__ __launch_bounds__(384)
void unsup_kernel(const float* __restrict__ pf, const float* __restrict__ frm0,
                  const float* __restrict__ frm1,
                  const float4* __restrict__ packed_all,
                  float* __restrict__ partials) {
    const int w = threadIdx.x;
    int blk = blockIdx.x;
    const int i = blk % NF; blk /= NF;       // level varies fastest across blocks:
    const int b = blk % NB;                  // 5 consecutive blocks share the same
    const int h = blk / NB;                  // frm0 row + frm1 neighborhood (L2/L3 reuse)
    const int off = h * NW + w;
    const float SC = (float)(NW - 1) / (float)NW;

    // frm0 pixel (3 channels, coalesced)
    const float* f0b = frm0 + b * 3 * HW + off;
    const float c0 = f0b[0];
    const float c1 = f0b[HW];
    const float c2 = f0b[2 * HW];

    // flow + neighbors (coalesced; zero-pad at edges)
    const float* fb = pf + (size_t)((i * NB + b) * 2) * HW + off;
    const float fx = fb[0];
    const float fy = fb[HW];
    float dnx = 0.f, dny = 0.f, rtx = 0.f, rty = 0.f;
    if (h < NH - 1) { dnx = fb[NW]; dny = fb[NW + HW]; }
    if (w < NW - 1) { rtx = fb[1];  rty = fb[HW + 1];  }

    float smooth = charb(fx - dnx) + charb(fy - dny) +
                   charb(fx - rtx) + charb(fy - rty);

    // bilinear zero-pad sample of frm1 at (xp, yp)
    float xp = (fx + (float)w) * SC;
    float yp = (fy + (float)h) * SC;
    float x0f = floorf(xp), y0f = floorf(yp);
    float wx1 = xp - x0f, wx0 = 1.f - wx1;
    float wy1 = yp - y0f, wy0 = 1.f - wy1;
    bool vx0 = (x0f >= 0.f) && (x0f <= (float)(NW - 1));
    bool vx1 = (x0f >= -1.f) && (x0f <= (float)(NW - 2));
    bool vy0 = (y0f >= 0.f) && (y0f <= (float)(NH - 1));
    bool vy1 = (y0f >= -1.f) && (y0f <= (float)(NH - 2));
    float m00 = (vx0 && vy0) ? wx0 * wy0 : 0.f;
    float m10 = (vx1 && vy0) ? wx1 * wy0 : 0.f;
    float m01 = (vx0 && vy1) ? wx0 * wy1 : 0.f;
    float m11 = (vx1 && vy1) ? wx1 * wy1 : 0.f;
    int x0i = min(max((int)x0f, 0), NW - 1);
    int y0i = min(max((int)y0f, 0), NH - 1);
    int x1i = min(x0i + 1, NW - 1);
    int y1i = min(y0i + 1, NH - 1);

    float s0, s1, s2;
    if (PACKED) {
        const float4* pk = packed_all + b * HW;
        float4 t00 = pk[y0i * NW + x0i];
        float4 t10 = pk[y0i * NW + x1i];
        float4 t01 = pk[y1i * NW + x0i];
        float4 t11 = pk[y1i * NW + x1i];
        s0 = m00 * t00.x + m10 * t10.x + m01 * t01.x + m11 * t11.x;
        s1 = m00 * t00.y + m10 * t10.y + m01 * t01.y + m11 * t11.y;
        s2 = m00 * t00.z + m10 * t10.z + m01 * t01.z + m11 * t11.z;
    } else {
        const float* img = frm1 + b * 3 * HW;
        int i00 = y0i * NW + x0i, i10 = y0i * NW + x1i;
        int i01 = y1i * NW + x0i, i11 = y1i * NW + x1i;
        s0 = m00 * img[i00] + m10 * img[i10] + m01 * img[i01] + m11 * img[i11];
        s1 = m00 * img[HW + i00] + m10 * img[HW + i10] +
             m01 * img[HW + i01] + m11 * img[HW + i11];
        s2 = m00 * img[2 * HW + i00] + m10 * img[2 * HW + i10] +
             m01 * img[2 * HW + i01] + m11 * img[2 * HW + i11];
    }
    float phot = charb(s0 - c0) + charb(s1 - c1) + charb(s2 - c2);

    float wt = exp2f((float)(4 - i) * -0.32192809488736f);  // 0.8^(4-i)
    float local = wt * (phot * (1.f / 3.f) + smooth * 0.5f);

    // block reduce (384 threads = 6 waves) -> per-block partial (no atomics)
    for (int o = 32; o > 0; o >>= 1) local += __shfl_down(local, o, 64);
    __shared__ float ssum[6];
    int lane = threadIdx.x & 63, wid = threadIdx.x >> 6;
    if (lane == 0) ssum[wid] = local;
    __syncthreads();
    if (threadIdx.x == 0) {
        float s = 0.f;
        #pragma unroll
        for (int k = 0; k < 6; ++k) s += ssum[k];
        partials[blockIdx.x] = s;
    }
}

__global__ __launch_bounds__(256)
void final_kernel(const float* __restrict__ ws, const float* __restrict__ partials,
                  float* __restrict__ out) {
    float local = 0.f;
    for (int q = threadIdx.x; q < UNSUP_BLOCKS; q += 256) local += partials[q];
    for (int o = 32; o > 0; o >>= 1) local += __shfl_down(local, o, 64);
    __shared__ float ssum[4];
    int lane = threadIdx.x & 63, wid = threadIdx.x >> 6;
    if (lane == 0) ssum[wid] = local;
    __syncthreads();
    if (threadIdx.x == 0) {
        float uns = ssum[0] + ssum[1] + ssum[2] + ssum[3];
        float denom = fmaxf(ws[1], 1.f);
        out[0] = uns * (1.f / (float)NB) + ws[0] / denom;
    }
}

extern "C" void kernel_launch(void* const* d_in, const int* in_sizes, int n_in,
                              void* d_out, int out_size, void* d_ws, size_t ws_size,
                              hipStream_t stream) {
    const float* pf   = (const float*)d_in[0];  // (5,16,2,384,384)
    const float* kps  = (const float*)d_in[1];  // (16,2,17,2)
    const float* frm0 = (const float*)d_in[2];  // (16,3,384,384)
    const float* frm1 = (const float*)d_in[3];  // (16,3,384,384)
    float* out = (float*)d_out;
    float* ws  = (float*)d_ws;

    const size_t need = 16 + (size_t)NPIX * 16 + (size_t)UNSUP_BLOCKS * 4;
    if (ws_size >= need) {
        float* partials = ws + 4 + (size_t)NPIX * 4;
        repack_kp_kernel<<<(NPIX + 255) / 256, 256, 0, stream>>>(frm1, kps, pf, ws, 1);
        unsup_kernel<true><<<UNSUP_BLOCKS, 384, 0, stream>>>(
            pf, frm0, frm1, (const float4*)ws + 1, partials);
        final_kernel<<<1, 256, 0, stream>>>(ws, partials, out);
    } else {
        float* partials = ws + 4;
        repack_kp_kernel<<<1, 256, 0, stream>>>(frm1, kps, pf, ws, 0);
        unsup_kernel<false><<<UNSUP_BLOCKS, 384, 0, stream>>>(
            pf, frm0, frm1, (const float4*)ws + 1, partials);
        final_kernel<<<1, 256, 0, stream>>>(ws, partials, out);
    }
}